// Round 3
// baseline (177.089 us; speedup 1.0000x reference)
//
#include <hip/hip_runtime.h>
#include <math.h>

// z[i] = R @ x[i], R from ZYX-intrinsic Euler angles in weight[3].
// x/out: [N,3] f32 row-major. N = 8,000,000 -> 24M floats = 6M float4 = 2M groups
// of (3 float4 = 4 points).
//
// Round-3 change: trig moved to a tiny setup kernel (R -> d_ws). The streaming
// kernel has NO per-block serial prologue (rounds 1-2 both recomputed R per
// block via 1-lane sincosf behind a barrier — the shared suspect for the
// 2.4 TB/s wall vs 6.5 TB/s fill on the same memory).

__global__ void rot_setup_kernel(const float* __restrict__ w,
                                 float* __restrict__ R)
{
    if (threadIdx.x == 0) {
        float a = w[0], b = w[1], c = w[2];
        float sa, ca, sb, cb, sc, cc;
        sincosf(a, &sa, &ca);
        sincosf(b, &sb, &cb);
        sincosf(c, &sc, &cc);
        R[0] = cc * cb;                // R00
        R[1] = sa * sb * cc - ca * sc; // R01
        R[2] = ca * sb * cc + sa * sc; // R02
        R[3] = cb * sc;                // R10
        R[4] = sa * sb * sc + ca * cc; // R11
        R[5] = ca * sb * sc - sa * cc; // R12
        R[6] = -sb;                    // R20
        R[7] = sa * cb;                // R21
        R[8] = ca * cb;                // R22
    }
}

__global__ __launch_bounds__(256) void rot_apply_kernel(
    const float* __restrict__ x,
    const float* __restrict__ Rw,
    float* __restrict__ out,
    long long n_groups)
{
    // Uniform-address loads; issue before the loop, L2-hit after first block.
    const float R00 = Rw[0], R01 = Rw[1], R02 = Rw[2];
    const float R10 = Rw[3], R11 = Rw[4], R12 = Rw[5];
    const float R20 = Rw[6], R21 = Rw[7], R22 = Rw[8];

    const float4* __restrict__ x4 = (const float4*)x;
    float4* __restrict__ o4 = (float4*)out;

    const long long stride = (long long)gridDim.x * blockDim.x;
#pragma unroll 2
    for (long long g = (long long)blockIdx.x * blockDim.x + threadIdx.x;
         g < n_groups; g += stride) {
        const long long base = 3ll * g;
        float4 v0 = x4[base + 0];
        float4 v1 = x4[base + 1];
        float4 v2 = x4[base + 2];

        // 4 points packed in 3 float4s:
        // p0=(v0.x,v0.y,v0.z) p1=(v0.w,v1.x,v1.y) p2=(v1.z,v1.w,v2.x) p3=(v2.y,v2.z,v2.w)
        float px0 = v0.x, py0 = v0.y, pz0 = v0.z;
        float px1 = v0.w, py1 = v1.x, pz1 = v1.y;
        float px2 = v1.z, py2 = v1.w, pz2 = v2.x;
        float px3 = v2.y, py3 = v2.z, pz3 = v2.w;

        float a0 = fmaf(R00, px0, fmaf(R01, py0, R02 * pz0));
        float b0 = fmaf(R10, px0, fmaf(R11, py0, R12 * pz0));
        float c0 = fmaf(R20, px0, fmaf(R21, py0, R22 * pz0));

        float a1 = fmaf(R00, px1, fmaf(R01, py1, R02 * pz1));
        float b1 = fmaf(R10, px1, fmaf(R11, py1, R12 * pz1));
        float c1 = fmaf(R20, px1, fmaf(R21, py1, R22 * pz1));

        float a2 = fmaf(R00, px2, fmaf(R01, py2, R02 * pz2));
        float b2 = fmaf(R10, px2, fmaf(R11, py2, R12 * pz2));
        float c2 = fmaf(R20, px2, fmaf(R21, py2, R22 * pz2));

        float a3 = fmaf(R00, px3, fmaf(R01, py3, R02 * pz3));
        float b3 = fmaf(R10, px3, fmaf(R11, py3, R12 * pz3));
        float c3 = fmaf(R20, px3, fmaf(R21, py3, R22 * pz3));

        float4 w0, w1, w2;
        w0.x = a0; w0.y = b0; w0.z = c0; w0.w = a1;
        w1.x = b1; w1.y = c1; w1.z = a2; w1.w = b2;
        w2.x = c2; w2.y = a3; w2.z = b3; w2.w = c3;

        o4[base + 0] = w0;
        o4[base + 1] = w1;
        o4[base + 2] = w2;
    }
}

extern "C" void kernel_launch(void* const* d_in, const int* in_sizes, int n_in,
                              void* d_out, int out_size, void* d_ws, size_t ws_size,
                              hipStream_t stream) {
    const float* x = (const float*)d_in[0];
    const float* w = (const float*)d_in[1];
    float* out = (float*)d_out;
    float* Rws = (float*)d_ws;   // 9 floats of scratch for R

    const long long n_floats = (long long)in_sizes[0];   // 24,000,000
    const long long n_groups = n_floats / 12;            // 2,000,000 (exact)

    rot_setup_kernel<<<1, 64, 0, stream>>>(w, Rws);

    const int block = 256;
    int grid = 2048;  // grid-stride, ~3.8 groups/thread
    long long needed = (n_groups + block - 1) / block;
    if (needed < grid) grid = (int)needed;

    rot_apply_kernel<<<grid, block, 0, stream>>>(x, Rws, out, n_groups);
}